// Round 2
// baseline (755.886 us; speedup 1.0000x reference)
//
#include <hip/hip_runtime.h>

typedef unsigned short ushort_t;

#define Bb 32
#define Hh 256
#define Ll 2048
#define Nn 64
#define Ff 32
#define BHL 16777216

typedef __bf16 bf16x8 __attribute__((ext_vector_type(8)));
typedef float f32x4 __attribute__((ext_vector_type(4)));
typedef unsigned int uint4v __attribute__((ext_vector_type(4)));

__device__ __forceinline__ ushort_t f2bf(float f) {
    unsigned int u = __float_as_uint(f);
    unsigned int r = ((u >> 16) & 1u) + 0x7fffu;
    return (ushort_t)((u + r) >> 16);
}
__device__ __forceinline__ float bf2f(ushort_t h) {
    return __uint_as_float(((unsigned int)h) << 16);
}
__device__ __forceinline__ float rlane(float v, int i) {
    return __int_as_float(__builtin_amdgcn_readlane(__float_as_int(v), i));
}
__device__ __forceinline__ float gelu_tanh(float v) {
    float u = 0.7978845608028654f * fmaf(0.044715f * v, v * v, v);
    float e = __expf(2.f * u);
    float th = 1.f - 2.f / (e + 1.f);
    return 0.5f * v * (1.f + th);
}
__device__ __forceinline__ float gate_fn(float v) {
    float sg = 1.f / (1.f + __expf(-v));
    float e2 = __expf(2.f * v);
    float th = 1.f - 2.f / (e2 + 1.f);
    return th * sg;
}

// ---------------- prep: tb GEMM, SSM coeffs, weight fragment repack ----------------
__global__ __launch_bounds__(256) void prep_kernel(
    const float* __restrict__ t, const float* __restrict__ Wt, const float* __restrict__ bt,
    const float* __restrict__ log_dt, const float* __restrict__ logA, const float* __restrict__ Aimg,
    const float* __restrict__ C_re, const float* __restrict__ C_im,
    const float* __restrict__ Wout, const float* __restrict__ Wf,
    const float* __restrict__ bout, const float* __restrict__ bfb,
    const float* __restrict__ W1, const float* __restrict__ b1,
    const float* __restrict__ W2, const float* __restrict__ b2,
    float* __restrict__ tb, float* __restrict__ wre, float* __restrict__ wim,
    float* __restrict__ c0r, float* __restrict__ c0i, float* __restrict__ c1r, float* __restrict__ c1i,
    float* __restrict__ bc, float* __restrict__ b12,
    ushort_t* __restrict__ wcf, ushort_t* __restrict__ w12f)
{
    int bx = blockIdx.x, tid = threadIdx.x;
    __shared__ float trow[256];
    if (bx < 32) {
        // tb[b][g] = bt[g] + sum_h t[b][h]*Wt[g][h]
        trow[tid] = t[bx * 256 + tid];
        __syncthreads();
        float acc = bt[tid];
        #pragma unroll 4
        for (int hh = 0; hh < 256; ++hh) acc = fmaf(trow[hh], Wt[tid * 256 + hh], acc);
        tb[bx * 256 + tid] = acc;
    } else if (bx < 96) {
        int idx = (bx - 32) * 256 + tid;      // 0..16383  (h*64+n)
        int h = idx >> 6;
        float dt = expf(log_dt[h]);
        float Ar = -expf(logA[idx]);
        float Ai = Aimg[idx];
        float dr = dt * Ar, di = dt * Ai;
        float er = expf(dr);
        float wr_ = er * cosf(di), wi_ = er * sinf(di);
        // q = (w-1)/A
        float nr = wr_ - 1.f, ni = wi_;
        float inv = 1.f / (Ar * Ar + Ai * Ai);
        float qr = (nr * Ar + ni * Ai) * inv;
        float qi = (ni * Ar - nr * Ai) * inv;
        wre[idx] = wr_; wim[idx] = wi_;
        float cr0 = C_re[idx], ci0 = C_im[idx];
        c0r[idx] = 2.f * (cr0 * qr - ci0 * qi);
        c0i[idx] = 2.f * (cr0 * qi + ci0 * qr);
        float cr1 = C_re[16384 + idx], ci1 = C_im[16384 + idx];
        c1r[idx] = 2.f * (cr1 * qr - ci1 * qi);
        c1i[idx] = 2.f * (cr1 * qi + ci1 * qr);
    } else if (bx < 128) {
        int gt = (bx - 96) * 256 + tid;       // 0..8191
        if (gt < 256) bc[gt] = bout[gt] + bfb[gt];
        if (gt < 512) b12[gt] = (gt < 256) ? b1[gt] : b2[gt - 256];
        // Wc_frag: 16 mtiles x 9 kchunks x 64 lanes x 8  (K=288: [Wout | Wf])
        for (int fg = gt; fg < 9216; fg += 8192) {
            int mt = fg / 576, rem = fg % 576;
            int kc = rem >> 6, lane = rem & 63;
            int m = mt * 16 + (lane & 15);
            int kb = kc * 32 + (lane >> 4) * 8;
            #pragma unroll
            for (int j = 0; j < 8; ++j) {
                int k = kb + j;
                float v = (k < 256) ? Wout[m * 256 + k] : Wf[m * 32 + (k - 256)];
                wcf[(size_t)fg * 8 + j] = f2bf(v);
            }
        }
    } else {
        int gt = (bx - 128) * 256 + tid;      // 0..8191
        // W12_frag: 32 mtiles x 8 kchunks x 64 lanes x 8  (M=512: [W1 ; W2])
        for (int fg = gt; fg < 16384; fg += 8192) {
            int mt = fg >> 9, rem = fg & 511;
            int kc = rem >> 6, lane = rem & 63;
            int m = mt * 16 + (lane & 15);
            int kb = kc * 32 + (lane >> 4) * 8;
            #pragma unroll
            for (int j = 0; j < 8; ++j) {
                int k = kb + j;
                float v = (m < 256) ? W1[m * 256 + k] : W2[(m - 256) * 256 + k];
                w12f[(size_t)fg * 8 + j] = f2bf(v);
            }
        }
    }
}

// ---------------- LayerNorm over H (channel axis) ----------------
__global__ __launch_bounds__(256) void ln_kernel(
    const float* __restrict__ x, const float* __restrict__ tb,
    const float* __restrict__ ln_g, const float* __restrict__ ln_b,
    float* __restrict__ z)
{
    int gid = blockIdx.x * 256 + threadIdx.x;   // one (b,l) per thread; lanes sweep l -> coalesced
    int b = gid >> 11, l = gid & 2047;
    const float* xp = x + (size_t)b * (Hh * Ll) + l;
    const float* tbp = tb + b * 256;
    float sum = 0.f, ssq = 0.f;
    #pragma unroll 8
    for (int h = 0; h < 256; ++h) {
        float v = xp[(size_t)h * Ll] + tbp[h];
        sum += v; ssq = fmaf(v, v, ssq);
    }
    float mean = sum * (1.f / 256.f);
    float var = fmaf(ssq, 1.f / 256.f, -mean * mean);
    float rstd = rsqrtf(var + 1e-5f);
    float* zp = z + (size_t)b * (Hh * Ll) + l;
    #pragma unroll 8
    for (int h = 0; h < 256; ++h) {
        float v = xp[(size_t)h * Ll] + tbp[h];
        zp[(size_t)h * Ll] = (v - mean) * rstd * ln_g[h] + ln_b[h];
    }
}

// ---------------- bidirectional diagonal-SSM scan ----------------
// one wave per (b,h); lane = mode n (N=64). fwd pass writes y_fwd (bf16),
// bwd pass combines + D*z + gelu -> y_act (bf16).
__global__ __launch_bounds__(256, 8) void scan_kernel(
    const float* __restrict__ z,
    const float* __restrict__ wre_, const float* __restrict__ wim_,
    const float* __restrict__ c0r_, const float* __restrict__ c0i_,
    const float* __restrict__ c1r_, const float* __restrict__ c1i_,
    const float* __restrict__ Dv,
    ushort_t* __restrict__ yfwd, ushort_t* __restrict__ yact)
{
    __shared__ float cbuf[4][16 * 65];   // per-wave contribution tile, stride 65 -> 2-way (free)
    __shared__ float ybuf[4][64];
    int w = threadIdx.x >> 6, lane = threadIdx.x & 63;
    int wid = blockIdx.x * 4 + w;
    int h = wid & 255, b = wid >> 8;
    int hn = h * 64 + lane;
    float wr = wre_[hn], wi = wim_[hn];
    float Dh = Dv[h];
    const float* zrow = z + (size_t)(b * 256 + h) * Ll;
    ushort_t* yfrow = yfwd + (size_t)(b * 256 + h) * Ll;
    ushort_t* yarow = yact + (size_t)(b * 256 + h) * Ll;
    float* cb = cbuf[w];
    float* yb = ybuf[w];
    int tl = lane & 15, grp = lane >> 4;

    // ---- forward (causal) ----
    {
        float cr = c0r_[hn], ci = c0i_[hn];
        float sre = 0.f, sim = 0.f;
        for (int T = 0; T < 32; ++T) {
            float zreg = zrow[T * 64 + lane];
            #pragma unroll
            for (int st = 0; st < 4; ++st) {
                #pragma unroll
                for (int tt = 0; tt < 16; ++tt) {
                    float zv = rlane(zreg, st * 16 + tt);
                    float t1 = fmaf(-wi, sim, zv);
                    float nre = fmaf(wr, sre, t1);
                    float nim = fmaf(wr, sim, wi * sre);
                    sre = nre; sim = nim;
                    cb[tt * 65 + lane] = fmaf(cr, sre, -(ci * sim));
                }
                float acc = 0.f;
                #pragma unroll
                for (int j = 0; j < 16; ++j) acc += cb[tl * 65 + grp * 16 + j];
                acc += __shfl_xor(acc, 16);
                acc += __shfl_xor(acc, 32);
                if (grp == 0) yb[st * 16 + tl] = acc;
            }
            yfrow[T * 64 + lane] = f2bf(yb[lane]);
        }
    }
    // ---- backward (anticausal): emit Re(C1*s) BEFORE updating with z[t] ----
    {
        float cr = c1r_[hn], ci = c1i_[hn];
        float sre = 0.f, sim = 0.f;
        for (int T = 31; T >= 0; --T) {
            float zreg = zrow[T * 64 + lane];
            #pragma unroll
            for (int st = 3; st >= 0; --st) {
                #pragma unroll
                for (int tt = 15; tt >= 0; --tt) {
                    cb[tt * 65 + lane] = fmaf(cr, sre, -(ci * sim));
                    float zv = rlane(zreg, st * 16 + tt);
                    float t1 = fmaf(-wi, sim, zv);
                    float nre = fmaf(wr, sre, t1);
                    float nim = fmaf(wr, sim, wi * sre);
                    sre = nre; sim = nim;
                }
                float acc = 0.f;
                #pragma unroll
                for (int j = 0; j < 16; ++j) acc += cb[tl * 65 + grp * 16 + j];
                acc += __shfl_xor(acc, 16);
                acc += __shfl_xor(acc, 32);
                if (grp == 0) yb[st * 16 + tl] = acc;
            }
            float ytot = bf2f(yfrow[T * 64 + lane]) + yb[lane] + Dh * zreg;
            ytot = gelu_tanh(ytot);
            yarow[T * 64 + lane] = f2bf(ytot);
        }
    }
}

// ---------------- GEMM1: g = gate(Wc @ [y_act; feat] + bc + x + tb) ----------------
__global__ __launch_bounds__(256, 4) void gemm1_kernel(
    const ushort_t* __restrict__ yact, const float* __restrict__ feat,
    const float* __restrict__ x, const float* __restrict__ tb,
    const float* __restrict__ bc, const ushort_t* __restrict__ wcf,
    ushort_t* __restrict__ g)
{
    __shared__ __align__(16) ushort_t XT[64 * 48];   // [n=64][k=32 (+16 pad)] bf16, k-contiguous
    int tid = threadIdx.x;
    int w = tid >> 6, lane = tid & 63;
    int bx = blockIdx.x;
    int b = bx >> 5;
    int l0 = (bx & 31) << 6;
    f32x4 acc[4][4] = {};
    int kk = tid >> 3, ng = tid & 7;
    for (int kc = 0; kc < 9; ++kc) {
        // stage X^T chunk (transpose in LDS)
        int k = kc * 32 + kk;
        union { uint4v v; ushort_t s[8]; } u;
        if (k < 256) {
            u.v = *(const uint4v*)(yact + (size_t)(b * 256 + k) * Ll + l0 + ng * 8);
        } else {
            const float* src = feat + (size_t)(b * 32 + (k - 256)) * Ll + l0 + ng * 8;
            #pragma unroll
            for (int j = 0; j < 8; ++j) u.s[j] = f2bf(src[j]);
        }
        #pragma unroll
        for (int j = 0; j < 8; ++j) XT[(ng * 8 + j) * 48 + kk] = u.s[j];
        __syncthreads();
        bf16x8 af[4], bfr[4];
        #pragma unroll
        for (int i = 0; i < 4; ++i) {
            const ushort_t* p = wcf + ((size_t)((w * 4 + i) * 9 + kc) * 64 + lane) * 8;
            af[i] = __builtin_bit_cast(bf16x8, *(const uint4v*)p);
        }
        #pragma unroll
        for (int nt = 0; nt < 4; ++nt) {
            const ushort_t* p = &XT[(nt * 16 + (lane & 15)) * 48 + (lane >> 4) * 8];
            bfr[nt] = __builtin_bit_cast(bf16x8, *(const uint4v*)p);
        }
        #pragma unroll
        for (int i = 0; i < 4; ++i)
            #pragma unroll
            for (int nt = 0; nt < 4; ++nt)
                acc[i][nt] = __builtin_amdgcn_mfma_f32_16x16x32_bf16(af[i], bfr[nt], acc[i][nt], 0, 0, 0);
        __syncthreads();
    }
    int q = lane >> 4, nl = lane & 15;
    #pragma unroll
    for (int i = 0; i < 4; ++i) {
        #pragma unroll
        for (int nt = 0; nt < 4; ++nt) {
            int n = l0 + nt * 16 + nl;
            #pragma unroll
            for (int r = 0; r < 4; ++r) {
                int m = (w * 4 + i) * 16 + q * 4 + r;
                size_t oi = (size_t)(b * 256 + m) * Ll + n;
                float v = acc[i][nt][r] + bc[m] + tb[b * 256 + m] + x[oi];
                g[oi] = f2bf(gate_fn(v));
            }
        }
    }
}

// ---------------- GEMM2: o1 = W1@g + b1 + x ; o2 = W2@g + b2 ----------------
__global__ __launch_bounds__(256, 4) void gemm2_kernel(
    const ushort_t* __restrict__ g, const float* __restrict__ x,
    const float* __restrict__ b12, const ushort_t* __restrict__ w12f,
    float* __restrict__ out)
{
    __shared__ __align__(16) ushort_t XT[64 * 48];
    int tid = threadIdx.x;
    int w = tid >> 6, lane = tid & 63;
    int bx = blockIdx.x;
    int half = blockIdx.y;
    int b = bx >> 5;
    int l0 = (bx & 31) << 6;
    f32x4 acc[4][4] = {};
    int kk = tid >> 3, ng = tid & 7;
    for (int kc = 0; kc < 8; ++kc) {
        int k = kc * 32 + kk;
        union { uint4v v; ushort_t s[8]; } u;
        u.v = *(const uint4v*)(g + (size_t)(b * 256 + k) * Ll + l0 + ng * 8);
        #pragma unroll
        for (int j = 0; j < 8; ++j) XT[(ng * 8 + j) * 48 + kk] = u.s[j];
        __syncthreads();
        bf16x8 af[4], bfr[4];
        #pragma unroll
        for (int i = 0; i < 4; ++i) {
            int mtg = half * 16 + w * 4 + i;
            const ushort_t* p = w12f + ((size_t)(mtg * 8 + kc) * 64 + lane) * 8;
            af[i] = __builtin_bit_cast(bf16x8, *(const uint4v*)p);
        }
        #pragma unroll
        for (int nt = 0; nt < 4; ++nt) {
            const ushort_t* p = &XT[(nt * 16 + (lane & 15)) * 48 + (lane >> 4) * 8];
            bfr[nt] = __builtin_bit_cast(bf16x8, *(const uint4v*)p);
        }
        #pragma unroll
        for (int i = 0; i < 4; ++i)
            #pragma unroll
            for (int nt = 0; nt < 4; ++nt)
                acc[i][nt] = __builtin_amdgcn_mfma_f32_16x16x32_bf16(af[i], bfr[nt], acc[i][nt], 0, 0, 0);
        __syncthreads();
    }
    int q = lane >> 4, nl = lane & 15;
    #pragma unroll
    for (int i = 0; i < 4; ++i) {
        #pragma unroll
        for (int nt = 0; nt < 4; ++nt) {
            int n = l0 + nt * 16 + nl;
            #pragma unroll
            for (int r = 0; r < 4; ++r) {
                int m = (w * 4 + i) * 16 + q * 4 + r;   // 0..255 within half
                size_t oi = (size_t)(b * 256 + m) * Ll + n;
                float v = acc[i][nt][r] + b12[half * 256 + m];
                if (half == 0) out[oi] = v + x[oi];
                else out[(size_t)BHL + oi] = v;
            }
        }
    }
}

extern "C" void kernel_launch(void* const* d_in, const int* in_sizes, int n_in,
                              void* d_out, int out_size, void* d_ws, size_t ws_size,
                              hipStream_t stream) {
    const float* x      = (const float*)d_in[0];
    const float* t      = (const float*)d_in[1];
    const float* feat   = (const float*)d_in[2];
    const float* Wt     = (const float*)d_in[3];
    const float* bt     = (const float*)d_in[4];
    const float* ln_g   = (const float*)d_in[5];
    const float* ln_b   = (const float*)d_in[6];
    const float* log_dt = (const float*)d_in[7];
    const float* logA   = (const float*)d_in[8];
    const float* Aimg   = (const float*)d_in[9];
    const float* C_re   = (const float*)d_in[10];
    const float* C_im   = (const float*)d_in[11];
    const float* Dv     = (const float*)d_in[12];
    const float* Wout   = (const float*)d_in[13];
    const float* bout   = (const float*)d_in[14];
    const float* W1     = (const float*)d_in[15];
    const float* b1     = (const float*)d_in[16];
    const float* W2     = (const float*)d_in[17];
    const float* b2     = (const float*)d_in[18];
    const float* Wf     = (const float*)d_in[19];
    const float* bfb    = (const float*)d_in[20];

    // d_out doubles as scratch: z fp32 [0,64M) | y_fwd bf16 [64M,96M) | y_act bf16 [96M,128M)
    char* ob = (char*)d_out;
    float*    z    = (float*)ob;
    ushort_t* yfwd = (ushort_t*)(ob + 67108864);
    ushort_t* yact = (ushort_t*)(ob + 100663296);
    float*    out  = (float*)d_out;

    char* ws = (char*)d_ws;
    ushort_t* gbuf = (ushort_t*)ws;                       // 33,554,432 B
    float* tb   = (float*)(ws + 33554432);
    float* wre  = (float*)(ws + 33554432 + 32768);
    float* wim  = (float*)(ws + 33554432 + 32768 + 65536);
    float* c0r  = (float*)(ws + 33554432 + 32768 + 65536 * 2);
    float* c0i  = (float*)(ws + 33554432 + 32768 + 65536 * 3);
    float* c1r  = (float*)(ws + 33554432 + 32768 + 65536 * 4);
    float* c1i  = (float*)(ws + 33554432 + 32768 + 65536 * 5);
    float* bc   = (float*)(ws + 33554432 + 32768 + 65536 * 6);
    float* b12  = (float*)(ws + 33554432 + 32768 + 65536 * 6 + 1024);
    ushort_t* wcf  = (ushort_t*)(ws + 33554432 + 32768 + 65536 * 6 + 1024 + 2048);
    ushort_t* w12f = (ushort_t*)(ws + 33554432 + 32768 + 65536 * 6 + 1024 + 2048 + 147456);

    prep_kernel<<<160, 256, 0, stream>>>(t, Wt, bt, log_dt, logA, Aimg, C_re, C_im,
                                         Wout, Wf, bout, bfb, W1, b1, W2, b2,
                                         tb, wre, wim, c0r, c0i, c1r, c1i, bc, b12, wcf, w12f);
    ln_kernel<<<256, 256, 0, stream>>>(x, tb, ln_g, ln_b, z);
    scan_kernel<<<2048, 256, 0, stream>>>(z, wre, wim, c0r, c0i, c1r, c1i, Dv, yfwd, yact);
    gemm1_kernel<<<1024, 256, 0, stream>>>(yact, feat, x, tb, bc, wcf, gbuf);
    gemm2_kernel<<<dim3(1024, 2), 256, 0, stream>>>(gbuf, x, b12, w12f, out);
}

// Round 3
// 548.665 us; speedup vs baseline: 1.3777x; 1.3777x over previous
//
#include <hip/hip_runtime.h>

typedef unsigned short ushort_t;

#define Bb 32
#define Hh 256
#define Ll 2048
#define Nn 64
#define BHL 16777216

typedef __bf16 bf16x8 __attribute__((ext_vector_type(8)));
typedef float f32x4 __attribute__((ext_vector_type(4)));
typedef unsigned int uint4v __attribute__((ext_vector_type(4)));

__device__ __forceinline__ ushort_t f2bf(float f) {
    unsigned int u = __float_as_uint(f);
    unsigned int r = ((u >> 16) & 1u) + 0x7fffu;
    return (ushort_t)((u + r) >> 16);
}
__device__ __forceinline__ float bf2f(ushort_t h) {
    return __uint_as_float(((unsigned int)h) << 16);
}
__device__ __forceinline__ float gelu_tanh(float v) {
    float u = 0.7978845608028654f * fmaf(0.044715f * v, v * v, v);
    float e = __expf(2.f * u);
    float th = 1.f - 2.f / (e + 1.f);
    return 0.5f * v * (1.f + th);
}
__device__ __forceinline__ float gate_fn(float v) {
    float sg = 1.f / (1.f + __expf(-v));
    float e2 = __expf(2.f * v);
    float th = 1.f - 2.f / (e2 + 1.f);
    return th * sg;
}
__device__ __forceinline__ uint4v load_rev8(const ushort_t* p) {
    union { uint4v v; ushort_t s8[8]; } a, b;
    a.v = *(const uint4v*)p;
    #pragma unroll
    for (int j = 0; j < 8; ++j) b.s8[j] = a.s8[7 - j];
    return b.v;
}

// ---------------- prep: tb GEMM + weight fragment repack ----------------
__global__ __launch_bounds__(256) void prep_kernel(
    const float* __restrict__ t, const float* __restrict__ Wt, const float* __restrict__ bt,
    const float* __restrict__ Wout, const float* __restrict__ Wf,
    const float* __restrict__ bout, const float* __restrict__ bfb,
    const float* __restrict__ W1, const float* __restrict__ b1,
    const float* __restrict__ W2, const float* __restrict__ b2,
    float* __restrict__ tb, float* __restrict__ bc, float* __restrict__ b12,
    ushort_t* __restrict__ wcf, ushort_t* __restrict__ w12f)
{
    int bx = blockIdx.x, tid = threadIdx.x;
    __shared__ float trow[256];
    if (bx < 32) {
        trow[tid] = t[bx * 256 + tid];
        __syncthreads();
        float acc = bt[tid];
        #pragma unroll 4
        for (int hh = 0; hh < 256; ++hh) acc = fmaf(trow[hh], Wt[tid * 256 + hh], acc);
        tb[bx * 256 + tid] = acc;
    } else if (bx < 64) {
        int gt = (bx - 32) * 256 + tid;       // 0..8191
        if (gt < 256) bc[gt] = bout[gt] + bfb[gt];
        if (gt < 512) b12[gt] = (gt < 256) ? b1[gt] : b2[gt - 256];
        // Wc_frag: 16 mtiles x 9 kchunks x 64 lanes x 8  (K=288: [Wout | Wf])
        for (int fg = gt; fg < 9216; fg += 8192) {
            int mt = fg / 576, rem = fg % 576;
            int kc = rem >> 6, lane = rem & 63;
            int m = mt * 16 + (lane & 15);
            int kb = kc * 32 + (lane >> 4) * 8;
            #pragma unroll
            for (int j = 0; j < 8; ++j) {
                int k = kb + j;
                float v = (k < 256) ? Wout[m * 256 + k] : Wf[m * 32 + (k - 256)];
                wcf[(size_t)fg * 8 + j] = f2bf(v);
            }
        }
    } else {
        int gt = (bx - 64) * 256 + tid;       // 0..8191
        // W12_frag: 32 mtiles x 8 kchunks x 64 lanes x 8  (M=512: [W1 ; W2])
        for (int fg = gt; fg < 16384; fg += 8192) {
            int mt = fg >> 9, rem = fg & 511;
            int kc = rem >> 6, lane = rem & 63;
            int m = mt * 16 + (lane & 15);
            int kb = kc * 32 + (lane >> 4) * 8;
            #pragma unroll
            for (int j = 0; j < 8; ++j) {
                int k = kb + j;
                float v = (m < 256) ? W1[m * 256 + k] : W2[(m - 256) * 256 + k];
                w12f[(size_t)fg * 8 + j] = f2bf(v);
            }
        }
    }
}

// ---------------- prep2: per-(h,dir) SSM conv matrix [Toeplitz | boundary] in frag layout ----------------
// Mfrag[(h*2+dir)] : [mt 8][kc 8][lane 64][j 8], M[i][k]: k<128 Toeplitz k_h[i-k-dir], k>=128 boundary
__global__ __launch_bounds__(256) void prep2_kernel(
    const float* __restrict__ log_dt, const float* __restrict__ logA, const float* __restrict__ Aimg,
    const float* __restrict__ C_re, const float* __restrict__ C_im,
    float* __restrict__ drg, float* __restrict__ dig,
    ushort_t* __restrict__ Mfrag)
{
    int bx = blockIdx.x, tid = threadIdx.x;
    int h = bx >> 1, dir = bx & 1;
    __shared__ float drL[64], diL[64], crL[64], ciL[64];
    __shared__ float ktab[128];
    __shared__ ushort_t bndL[128 * 128];
    if (tid < 64) {
        int n = tid;
        int idx = h * 64 + n;
        float dt = expf(log_dt[h]);
        float Ar = -expf(logA[idx]);
        float Ai = Aimg[idx];
        float dr = dt * Ar, di = dt * Ai;
        float er = expf(dr);
        float wr_ = er * cosf(di), wi_ = er * sinf(di);
        float nr = wr_ - 1.f, ni = wi_;
        float inv = 1.f / (Ar * Ar + Ai * Ai);
        float qr = (nr * Ar + ni * Ai) * inv;
        float qi = (ni * Ar - nr * Ai) * inv;
        float cr = C_re[dir * 16384 + idx], ci = C_im[dir * 16384 + idx];
        drL[n] = dr; diL[n] = di;
        crL[n] = 2.f * (cr * qr - ci * qi);
        ciL[n] = 2.f * (cr * qi + ci * qr);
        if (dir == 0) { drg[idx] = dr; dig[idx] = di; }
    }
    __syncthreads();
    if (tid < 128) {
        int i = tid;
        float e = (float)(i + 1 - dir);
        #pragma unroll 4
        for (int n = 0; n < 64; ++n) {
            float ex = expf(e * drL[n]);
            float ph = e * diL[n];
            float pr = ex * cosf(ph), pi = ex * sinf(ph);
            bndL[i * 128 + n]      = f2bf(crL[n] * pr - ciL[n] * pi);
            bndL[i * 128 + 64 + n] = f2bf(-(crL[n] * pi + ciL[n] * pr));
        }
    } else {
        int d = tid - 128;
        float e = (float)d;
        float acc = 0.f;
        #pragma unroll 4
        for (int n = 0; n < 64; ++n) {
            float ex = expf(e * drL[n]);
            float ph = e * diL[n];
            acc += crL[n] * (ex * cosf(ph)) - ciL[n] * (ex * sinf(ph));
        }
        ktab[d] = acc;
    }
    __syncthreads();
    size_t base = (size_t)bx << 15;
    for (int idx = tid; idx < 32768; idx += 256) {
        int j = idx & 7, lane = (idx >> 3) & 63, kc = (idx >> 9) & 7, mt = idx >> 12;
        int m = mt * 16 + (lane & 15);
        int k = kc * 32 + (lane >> 4) * 8 + j;
        float v;
        if (k < 128) {
            int d = m - k - dir;
            v = (d >= 0) ? ktab[d] : 0.f;
        } else {
            v = bf2f(bndL[m * 128 + (k - 128)]);
        }
        Mfrag[base + idx] = f2bf(v);
    }
}

// ---------------- LayerNorm over H -> bf16 z ----------------
__global__ __launch_bounds__(256) void ln_kernel(
    const float* __restrict__ x, const float* __restrict__ tb,
    const float* __restrict__ ln_g, const float* __restrict__ ln_b,
    ushort_t* __restrict__ zbf)
{
    int gid = blockIdx.x * 256 + threadIdx.x;
    int b = gid >> 11, l = gid & 2047;
    const float* xp = x + (size_t)b * (Hh * Ll) + l;
    const float* tbp = tb + b * 256;
    float sum = 0.f, ssq = 0.f;
    #pragma unroll 8
    for (int h = 0; h < 256; ++h) {
        float v = xp[(size_t)h * Ll] + tbp[h];
        sum += v; ssq = fmaf(v, v, ssq);
    }
    float mean = sum * (1.f / 256.f);
    float var = fmaf(ssq, 1.f / 256.f, -mean * mean);
    float rstd = rsqrtf(var + 1e-5f);
    ushort_t* zp = zbf + (size_t)b * (Hh * Ll) + l;
    #pragma unroll 8
    for (int h = 0; h < 256; ++h) {
        float v = xp[(size_t)h * Ll] + tbp[h];
        zp[(size_t)h * Ll] = f2bf((v - mean) * rstd * ln_g[h] + ln_b[h]);
    }
}

// ---------------- qscan: Q = Vand @ z-chunks (MFMA) + 16-step chunk scan -> boundary states ----------------
// grid (h 256, bg 8); states[b][h][c-1 in 0..14][s 0..127] bf16 (chunk 0 state == 0, not stored)
__global__ __launch_bounds__(256) void qscan_kernel(
    const ushort_t* __restrict__ zbf, const float* __restrict__ drg, const float* __restrict__ dig,
    ushort_t* __restrict__ states, int dir)
{
    __shared__ ushort_t V[128 * 136];
    __shared__ float Qbuf[128 * 17];
    int tid = threadIdx.x, lane = tid & 63, w = tid >> 6;
    int h = blockIdx.x, bg = blockIdx.y;
    {
        int s = tid >> 1, jh = tid & 1;
        int n = s & 63;
        float dr = drg[h * 64 + n], di = dig[h * 64 + n];
        bool isim = s >= 64;
        for (int jj = 0; jj < 64; ++jj) {
            int j = jh * 64 + jj;
            float e = (float)(127 - j);
            float ex = expf(e * dr);
            float ph = e * di;
            V[s * 136 + j] = f2bf(isim ? ex * sinf(ph) : ex * cosf(ph));
        }
    }
    float dr0 = drg[h * 64 + lane], di0 = dig[h * 64 + lane];
    float ex128 = expf(128.f * dr0);
    float w128r = ex128 * cosf(128.f * di0);
    float w128i = ex128 * sinf(128.f * di0);
    __syncthreads();
    int q = lane >> 4, c = lane & 15;
    for (int bsub = 0; bsub < 4; ++bsub) {
        int b = bg * 4 + bsub;
        const ushort_t* zrow = zbf + ((size_t)(b * 256 + h) << 11);
        bf16x8 bfr[4];
        #pragma unroll
        for (int kc = 0; kc < 4; ++kc) {
            int tau = c * 128 + kc * 32 + q * 8;
            uint4v v;
            if (dir == 0) v = *(const uint4v*)(zrow + tau);
            else          v = load_rev8(zrow + (2040 - tau));
            bfr[kc] = __builtin_bit_cast(bf16x8, v);
        }
        f32x4 acc[2] = {};
        #pragma unroll
        for (int i = 0; i < 2; ++i) {
            int mt = w * 2 + i;
            #pragma unroll
            for (int kc = 0; kc < 4; ++kc) {
                const ushort_t* p = &V[(mt * 16 + (lane & 15)) * 136 + kc * 32 + q * 8];
                bf16x8 af = __builtin_bit_cast(bf16x8, *(const uint4v*)p);
                acc[i] = __builtin_amdgcn_mfma_f32_16x16x32_bf16(af, bfr[kc], acc[i], 0, 0, 0);
            }
        }
        __syncthreads();   // protect Qbuf reuse (prev iter scan)
        #pragma unroll
        for (int i = 0; i < 2; ++i) {
            int mt = w * 2 + i;
            #pragma unroll
            for (int r = 0; r < 4; ++r)
                Qbuf[(mt * 16 + q * 4 + r) * 17 + c] = acc[i][r];
        }
        __syncthreads();
        if (w == 0) {
            float sre = 0.f, sim = 0.f;
            ushort_t* sb = states + (size_t)(b * 256 + h) * (15 * 128);
            for (int cc = 0; cc < 16; ++cc) {
                if (cc > 0) {
                    sb[(cc - 1) * 128 + lane] = f2bf(sre);
                    sb[(cc - 1) * 128 + 64 + lane] = f2bf(sim);
                }
                float qre = Qbuf[lane * 17 + cc];
                float qim = Qbuf[(64 + lane) * 17 + cc];
                float nre = fmaf(w128r, sre, fmaf(-w128i, sim, qre));
                float nim = fmaf(w128r, sim, fmaf(w128i, sre, qim));
                sre = nre; sim = nim;
            }
        }
        __syncthreads();
    }
}

// ---------------- conv_gemm: y = M @ [z-chunk; state] per (h,dir) ----------------
// grid (h 256, cb 8): 4 b's x 16 chunks = 64 columns; M=128 rows, K=256
__global__ __launch_bounds__(256) void conv_gemm_kernel(
    const ushort_t* __restrict__ zbf, const ushort_t* __restrict__ states,
    const ushort_t* __restrict__ Mfrag, ushort_t* __restrict__ ydst, int dir)
{
    __shared__ ushort_t Zs[4 * 16 * 136];
    __shared__ ushort_t Ss[4 * 16 * 136];
    int tid = threadIdx.x, lane = tid & 63, w = tid >> 6;
    int h = blockIdx.x, cb = blockIdx.y;
    int b0 = cb * 4;
    for (int i = tid; i < 1024; i += 256) {
        int bsub = i >> 8, t8 = (i & 255) * 8;
        const ushort_t* zrow = zbf + ((size_t)((b0 + bsub) * 256 + h) << 11);
        uint4v v;
        if (dir == 0) v = *(const uint4v*)(zrow + t8);
        else          v = load_rev8(zrow + (2040 - t8));
        int c = t8 >> 7, j0 = t8 & 127;
        *(uint4v*)&Zs[(bsub * 16 + c) * 136 + j0] = v;
    }
    for (int i = tid; i < 960; i += 256) {
        int bsub = i / 240, r2 = i % 240;
        int c = r2 >> 4, s0 = (r2 & 15) * 8;
        const ushort_t* sp = states + ((size_t)((b0 + bsub) * 256 + h) * 15 + c) * 128 + s0;
        *(uint4v*)&Ss[(bsub * 16 + (c + 1)) * 136 + s0] = *(const uint4v*)sp;
    }
    for (int i = tid; i < 64; i += 256) {
        int bsub = i >> 4, s0 = (i & 15) * 8;
        uint4v zz = {};
        *(uint4v*)&Ss[(bsub * 16) * 136 + s0] = zz;
    }
    __syncthreads();
    int q = lane >> 4, cl = lane & 15;
    f32x4 acc[2][4] = {};
    const ushort_t* mbase = Mfrag + ((size_t)(h * 2 + dir) << 15);
    for (int kc = 0; kc < 8; ++kc) {
        bf16x8 af[2], bfr[4];
        #pragma unroll
        for (int i = 0; i < 2; ++i) {
            int mt = w * 2 + i;
            af[i] = __builtin_bit_cast(bf16x8, *(const uint4v*)(mbase + (((mt * 8 + kc) * 64 + lane) << 3)));
        }
        #pragma unroll
        for (int nt = 0; nt < 4; ++nt) {
            const ushort_t* p = (kc < 4)
                ? &Zs[(nt * 16 + cl) * 136 + kc * 32 + q * 8]
                : &Ss[(nt * 16 + cl) * 136 + (kc - 4) * 32 + q * 8];
            bfr[nt] = __builtin_bit_cast(bf16x8, *(const uint4v*)p);
        }
        #pragma unroll
        for (int i = 0; i < 2; ++i)
            #pragma unroll
            for (int nt = 0; nt < 4; ++nt)
                acc[i][nt] = __builtin_amdgcn_mfma_f32_16x16x32_bf16(af[i], bfr[nt], acc[i][nt], 0, 0, 0);
    }
    ushort_t* yT = Ss;
    for (int nt = 0; nt < 4; ++nt) {
        __syncthreads();
        #pragma unroll
        for (int i = 0; i < 2; ++i) {
            int mt = w * 2 + i;
            #pragma unroll
            for (int r = 0; r < 4; ++r)
                yT[cl * 136 + mt * 16 + q * 4 + r] = f2bf(acc[i][nt][r]);
        }
        __syncthreads();
        int c = tid >> 4, i0 = (tid & 15) * 8;
        ushort_t* yrow = ydst + ((size_t)((b0 + nt) * 256 + h) << 11);
        *(uint4v*)(yrow + c * 128 + i0) = *(const uint4v*)&yT[c * 136 + i0];
    }
}

// ---------------- GEMM1: g = gate(Wc @ [gelu(yf+yb_rev+D*z); feat] + bc + x + tb) ----------------
__global__ __launch_bounds__(256, 4) void gemm1_kernel(
    const ushort_t* __restrict__ yf, const ushort_t* __restrict__ ybh,
    const ushort_t* __restrict__ zbf, const float* __restrict__ feat,
    const float* __restrict__ x, const float* __restrict__ tb,
    const float* __restrict__ bc, const float* __restrict__ Dv,
    const ushort_t* __restrict__ wcf, ushort_t* __restrict__ g)
{
    __shared__ __align__(16) ushort_t XT[64 * 48];
    int tid = threadIdx.x;
    int w = tid >> 6, lane = tid & 63;
    int bx = blockIdx.x;
    int b = bx >> 5;
    int l0 = (bx & 31) << 6;
    f32x4 acc[4][4] = {};
    int kk = tid >> 3, ng = tid & 7;
    for (int kc = 0; kc < 9; ++kc) {
        int k = kc * 32 + kk;
        union { uint4v v; ushort_t s[8]; } u;
        if (k < 256) {
            size_t rbase = ((size_t)(b * 256 + k) << 11);
            union { uint4v v; ushort_t s8[8]; } uf, uz, ub;
            uf.v = *(const uint4v*)(yf + rbase + l0 + ng * 8);
            uz.v = *(const uint4v*)(zbf + rbase + l0 + ng * 8);
            ub.v = *(const uint4v*)(ybh + rbase + (2040 - l0 - ng * 8));
            float Dh = Dv[k];
            #pragma unroll
            for (int j = 0; j < 8; ++j) {
                float v = bf2f(uf.s8[j]) + bf2f(ub.s8[7 - j]) + Dh * bf2f(uz.s8[j]);
                u.s[j] = f2bf(gelu_tanh(v));
            }
        } else {
            const float* src = feat + (size_t)(b * 32 + (k - 256)) * Ll + l0 + ng * 8;
            #pragma unroll
            for (int j = 0; j < 8; ++j) u.s[j] = f2bf(src[j]);
        }
        #pragma unroll
        for (int j = 0; j < 8; ++j) XT[(ng * 8 + j) * 48 + kk] = u.s[j];
        __syncthreads();
        bf16x8 af[4], bfr[4];
        #pragma unroll
        for (int i = 0; i < 4; ++i) {
            const ushort_t* p = wcf + ((size_t)((w * 4 + i) * 9 + kc) * 64 + lane) * 8;
            af[i] = __builtin_bit_cast(bf16x8, *(const uint4v*)p);
        }
        #pragma unroll
        for (int nt = 0; nt < 4; ++nt) {
            const ushort_t* p = &XT[(nt * 16 + (lane & 15)) * 48 + (lane >> 4) * 8];
            bfr[nt] = __builtin_bit_cast(bf16x8, *(const uint4v*)p);
        }
        #pragma unroll
        for (int i = 0; i < 4; ++i)
            #pragma unroll
            for (int nt = 0; nt < 4; ++nt)
                acc[i][nt] = __builtin_amdgcn_mfma_f32_16x16x32_bf16(af[i], bfr[nt], acc[i][nt], 0, 0, 0);
        __syncthreads();
    }
    int q = lane >> 4, nl = lane & 15;
    #pragma unroll
    for (int i = 0; i < 4; ++i) {
        #pragma unroll
        for (int nt = 0; nt < 4; ++nt) {
            int n = l0 + nt * 16 + nl;
            #pragma unroll
            for (int r = 0; r < 4; ++r) {
                int m = (w * 4 + i) * 16 + q * 4 + r;
                size_t oi = (size_t)(b * 256 + m) * Ll + n;
                float v = acc[i][nt][r] + bc[m] + tb[b * 256 + m] + x[oi];
                g[oi] = f2bf(gate_fn(v));
            }
        }
    }
}

// ---------------- GEMM2: o1 = W1@g + b1 + x ; o2 = W2@g + b2 ----------------
__global__ __launch_bounds__(256, 4) void gemm2_kernel(
    const ushort_t* __restrict__ g, const float* __restrict__ x,
    const float* __restrict__ b12, const ushort_t* __restrict__ w12f,
    float* __restrict__ out)
{
    __shared__ __align__(16) ushort_t XT[64 * 48];
    int tid = threadIdx.x;
    int w = tid >> 6, lane = tid & 63;
    int bx = blockIdx.x;
    int half = blockIdx.y;
    int b = bx >> 5;
    int l0 = (bx & 31) << 6;
    f32x4 acc[4][4] = {};
    int kk = tid >> 3, ng = tid & 7;
    for (int kc = 0; kc < 8; ++kc) {
        int k = kc * 32 + kk;
        union { uint4v v; ushort_t s[8]; } u;
        u.v = *(const uint4v*)(g + (size_t)(b * 256 + k) * Ll + l0 + ng * 8);
        #pragma unroll
        for (int j = 0; j < 8; ++j) XT[(ng * 8 + j) * 48 + kk] = u.s[j];
        __syncthreads();
        bf16x8 af[4], bfr[4];
        #pragma unroll
        for (int i = 0; i < 4; ++i) {
            int mtg = half * 16 + w * 4 + i;
            const ushort_t* p = w12f + ((size_t)(mtg * 8 + kc) * 64 + lane) * 8;
            af[i] = __builtin_bit_cast(bf16x8, *(const uint4v*)p);
        }
        #pragma unroll
        for (int nt = 0; nt < 4; ++nt) {
            const ushort_t* p = &XT[(nt * 16 + (lane & 15)) * 48 + (lane >> 4) * 8];
            bfr[nt] = __builtin_bit_cast(bf16x8, *(const uint4v*)p);
        }
        #pragma unroll
        for (int i = 0; i < 4; ++i)
            #pragma unroll
            for (int nt = 0; nt < 4; ++nt)
                acc[i][nt] = __builtin_amdgcn_mfma_f32_16x16x32_bf16(af[i], bfr[nt], acc[i][nt], 0, 0, 0);
        __syncthreads();
    }
    int q = lane >> 4, nl = lane & 15;
    #pragma unroll
    for (int i = 0; i < 4; ++i) {
        #pragma unroll
        for (int nt = 0; nt < 4; ++nt) {
            int n = l0 + nt * 16 + nl;
            #pragma unroll
            for (int r = 0; r < 4; ++r) {
                int m = (w * 4 + i) * 16 + q * 4 + r;
                size_t oi = (size_t)(b * 256 + m) * Ll + n;
                float v = acc[i][nt][r] + b12[half * 256 + m];
                if (half == 0) out[oi] = v + x[oi];
                else out[(size_t)BHL + oi] = v;
            }
        }
    }
}

extern "C" void kernel_launch(void* const* d_in, const int* in_sizes, int n_in,
                              void* d_out, int out_size, void* d_ws, size_t ws_size,
                              hipStream_t stream) {
    const float* x      = (const float*)d_in[0];
    const float* t      = (const float*)d_in[1];
    const float* feat   = (const float*)d_in[2];
    const float* Wt     = (const float*)d_in[3];
    const float* bt     = (const float*)d_in[4];
    const float* ln_g   = (const float*)d_in[5];
    const float* ln_b   = (const float*)d_in[6];
    const float* log_dt = (const float*)d_in[7];
    const float* logA   = (const float*)d_in[8];
    const float* Aimg   = (const float*)d_in[9];
    const float* C_re   = (const float*)d_in[10];
    const float* C_im   = (const float*)d_in[11];
    const float* Dv     = (const float*)d_in[12];
    const float* Wout   = (const float*)d_in[13];
    const float* bout   = (const float*)d_in[14];
    const float* W1     = (const float*)d_in[15];
    const float* b1     = (const float*)d_in[16];
    const float* W2     = (const float*)d_in[17];
    const float* b2     = (const float*)d_in[18];
    const float* Wf     = (const float*)d_in[19];
    const float* bfb    = (const float*)d_in[20];

    // d_out (128 MiB): zbf [0,32Mi) | yf [32,64) | ybh [64,96) | states [96,126)
    char* ob = (char*)d_out;
    ushort_t* zbf    = (ushort_t*)ob;
    ushort_t* yfwd   = (ushort_t*)(ob + 33554432);
    ushort_t* ybh    = (ushort_t*)(ob + 67108864);
    ushort_t* states = (ushort_t*)(ob + 100663296);
    float*    out    = (float*)d_out;

    // ws: Mfrag (32 MiB, later aliased by g) | small tables
    char* ws = (char*)d_ws;
    ushort_t* Mfrag = (ushort_t*)ws;
    ushort_t* gbuf  = (ushort_t*)ws;                  // alias: g overwrites Mfrag (dead by gemm1)
    float* tb   = (float*)(ws + 33554432);
    float* drg  = (float*)(ws + 33554432 + 32768);
    float* dig  = (float*)(ws + 33554432 + 98304);
    float* bc   = (float*)(ws + 33554432 + 163840);
    float* b12  = (float*)(ws + 33554432 + 164864);
    ushort_t* wcf  = (ushort_t*)(ws + 33554432 + 166912);
    ushort_t* w12f = (ushort_t*)(ws + 33554432 + 314368);

    prep_kernel<<<96, 256, 0, stream>>>(t, Wt, bt, Wout, Wf, bout, bfb, W1, b1, W2, b2,
                                        tb, bc, b12, wcf, w12f);
    prep2_kernel<<<512, 256, 0, stream>>>(log_dt, logA, Aimg, C_re, C_im, drg, dig, Mfrag);
    ln_kernel<<<256, 256, 0, stream>>>(x, tb, ln_g, ln_b, zbf);
    qscan_kernel<<<dim3(256, 8), 256, 0, stream>>>(zbf, drg, dig, states, 0);
    conv_gemm_kernel<<<dim3(256, 8), 256, 0, stream>>>(zbf, states, Mfrag, yfwd, 0);
    qscan_kernel<<<dim3(256, 8), 256, 0, stream>>>(zbf, drg, dig, states, 1);
    conv_gemm_kernel<<<dim3(256, 8), 256, 0, stream>>>(zbf, states, Mfrag, ybh, 1);
    gemm1_kernel<<<1024, 256, 0, stream>>>(yfwd, ybh, zbf, feat, x, tb, bc, Dv, wcf, gbuf);
    gemm2_kernel<<<dim3(1024, 2), 256, 0, stream>>>(gbuf, x, b12, w12f, out);
}

// Round 4
// 428.520 us; speedup vs baseline: 1.7639x; 1.2804x over previous
//
#include <hip/hip_runtime.h>

typedef unsigned short ushort_t;

#define Bb 32
#define Hh 256
#define Ll 2048
#define Nn 64
#define BHL 16777216

typedef __bf16 bf16x8 __attribute__((ext_vector_type(8)));
typedef float f32x4 __attribute__((ext_vector_type(4)));
typedef unsigned int uint4v __attribute__((ext_vector_type(4)));

__device__ __forceinline__ ushort_t f2bf(float f) {
    unsigned int u = __float_as_uint(f);
    unsigned int r = ((u >> 16) & 1u) + 0x7fffu;
    return (ushort_t)((u + r) >> 16);
}
__device__ __forceinline__ float bf2f(ushort_t h) {
    return __uint_as_float(((unsigned int)h) << 16);
}
__device__ __forceinline__ float gelu_tanh(float v) {
    float u = 0.7978845608028654f * fmaf(0.044715f * v, v * v, v);
    float e = __expf(2.f * u);
    float th = 1.f - 2.f / (e + 1.f);
    return 0.5f * v * (1.f + th);
}
__device__ __forceinline__ float gate_fn(float v) {
    float sg = 1.f / (1.f + __expf(-v));
    float e2 = __expf(2.f * v);
    float th = 1.f - 2.f / (e2 + 1.f);
    return th * sg;
}
__device__ __forceinline__ uint4v rev8v(uint4v a) {
    union { uint4v v; ushort_t s8[8]; } x, y;
    x.v = a;
    #pragma unroll
    for (int j = 0; j < 8; ++j) y.s8[j] = x.s8[7 - j];
    return y.v;
}

// ---------------- prep: tb GEMM + weight fragment repack ----------------
__global__ __launch_bounds__(256) void prep_kernel(
    const float* __restrict__ t, const float* __restrict__ Wt, const float* __restrict__ bt,
    const float* __restrict__ Wout, const float* __restrict__ Wf,
    const float* __restrict__ bout, const float* __restrict__ bfb,
    const float* __restrict__ W1, const float* __restrict__ b1,
    const float* __restrict__ W2, const float* __restrict__ b2,
    float* __restrict__ tb, float* __restrict__ bc, float* __restrict__ b12,
    ushort_t* __restrict__ wcf, ushort_t* __restrict__ w12f)
{
    int bx = blockIdx.x, tid = threadIdx.x;
    __shared__ float trow[256];
    if (bx < 32) {
        trow[tid] = t[bx * 256 + tid];
        __syncthreads();
        float acc = bt[tid];
        #pragma unroll 4
        for (int hh = 0; hh < 256; ++hh) acc = fmaf(trow[hh], Wt[tid * 256 + hh], acc);
        tb[bx * 256 + tid] = acc;
    } else if (bx < 64) {
        int gt = (bx - 32) * 256 + tid;       // 0..8191
        if (gt < 256) bc[gt] = bout[gt] + bfb[gt];
        if (gt < 512) b12[gt] = (gt < 256) ? b1[gt] : b2[gt - 256];
        // Wc_frag: 16 mtiles x 9 kchunks x 64 lanes x 8  (K=288: [Wout | Wf])
        for (int fg = gt; fg < 9216; fg += 8192) {
            int mt = fg / 576, rem = fg % 576;
            int kc = rem >> 6, lane = rem & 63;
            int m = mt * 16 + (lane & 15);
            int kb = kc * 32 + (lane >> 4) * 8;
            #pragma unroll
            for (int j = 0; j < 8; ++j) {
                int k = kb + j;
                float v = (k < 256) ? Wout[m * 256 + k] : Wf[m * 32 + (k - 256)];
                wcf[(size_t)fg * 8 + j] = f2bf(v);
            }
        }
    } else {
        int gt = (bx - 64) * 256 + tid;       // 0..8191
        // W12_frag: 32 mtiles x 8 kchunks x 64 lanes x 8  (M=512: [W1 ; W2])
        for (int fg = gt; fg < 16384; fg += 8192) {
            int mt = fg >> 9, rem = fg & 511;
            int kc = rem >> 6, lane = rem & 63;
            int m = mt * 16 + (lane & 15);
            int kb = kc * 32 + (lane >> 4) * 8;
            #pragma unroll
            for (int j = 0; j < 8; ++j) {
                int k = kb + j;
                float v = (m < 256) ? W1[m * 256 + k] : W2[(m - 256) * 256 + k];
                w12f[(size_t)fg * 8 + j] = f2bf(v);
            }
        }
    }
}

// ---------------- prep2: per-(h,dir) conv matrix [Toeplitz | boundary] + Vandermonde frags ----------------
// Mfrag[(h*2+dir)] : [mt 8][kc 8][lane 64][j 8]; Vfrag[h] : [mt 8][kc 4][lane 64][j 8]
__global__ __launch_bounds__(256) void prep2_kernel(
    const float* __restrict__ log_dt, const float* __restrict__ logA, const float* __restrict__ Aimg,
    const float* __restrict__ C_re, const float* __restrict__ C_im,
    float* __restrict__ drg, float* __restrict__ dig,
    ushort_t* __restrict__ Mfrag, ushort_t* __restrict__ Vfrag)
{
    int bx = blockIdx.x, tid = threadIdx.x;
    int h = bx >> 1, dir = bx & 1;
    __shared__ float drL[64], diL[64], crL[64], ciL[64];
    __shared__ float ktab[128];
    __shared__ ushort_t bndL[128 * 128];
    if (tid < 64) {
        int n = tid;
        int idx = h * 64 + n;
        float dt = __expf(log_dt[h]);
        float Ar = -__expf(logA[idx]);
        float Ai = Aimg[idx];
        float dr = dt * Ar, di = dt * Ai;
        float er = __expf(dr);
        float wr_ = er * __cosf(di), wi_ = er * __sinf(di);
        float nr = wr_ - 1.f, ni = wi_;
        float inv = 1.f / (Ar * Ar + Ai * Ai);
        float qr = (nr * Ar + ni * Ai) * inv;
        float qi = (ni * Ar - nr * Ai) * inv;
        float cr = C_re[dir * 16384 + idx], ci = C_im[dir * 16384 + idx];
        drL[n] = dr; diL[n] = di;
        crL[n] = 2.f * (cr * qr - ci * qi);
        ciL[n] = 2.f * (cr * qi + ci * qr);
        if (dir == 0) { drg[idx] = dr; dig[idx] = di; }
    }
    __syncthreads();
    if (tid < 128) {
        int i = tid;
        float e = (float)(i + 1 - dir);
        #pragma unroll 4
        for (int n = 0; n < 64; ++n) {
            float ex = __expf(e * drL[n]);
            float ph = e * diL[n];
            float pr = ex * __cosf(ph), pi = ex * __sinf(ph);
            bndL[i * 128 + n]      = f2bf(crL[n] * pr - ciL[n] * pi);
            bndL[i * 128 + 64 + n] = f2bf(-(crL[n] * pi + ciL[n] * pr));
        }
    } else {
        int d = tid - 128;
        float e = (float)d;
        float acc = 0.f;
        #pragma unroll 4
        for (int n = 0; n < 64; ++n) {
            float ex = __expf(e * drL[n]);
            float ph = e * diL[n];
            acc += crL[n] * (ex * __cosf(ph)) - ciL[n] * (ex * __sinf(ph));
        }
        ktab[d] = acc;
    }
    __syncthreads();
    size_t base = (size_t)bx << 15;
    for (int idx = tid; idx < 32768; idx += 256) {
        int j = idx & 7, lane = (idx >> 3) & 63, kc = (idx >> 9) & 7, mt = idx >> 12;
        int m = mt * 16 + (lane & 15);
        int k = kc * 32 + (lane >> 4) * 8 + j;
        float v;
        if (k < 128) {
            int d = m - k - dir;
            v = (d >= 0) ? ktab[d] : 0.f;
        } else {
            v = bf2f(bndL[m * 128 + (k - 128)]);
        }
        Mfrag[base + idx] = f2bf(v);
    }
    if (dir == 0) {
        // Vfrag: V[s][j] = s<64 ? Re(w_n^(127-j)) : Im(...), n = s&63
        size_t vbase = (size_t)h << 14;
        for (int idx = tid; idx < 16384; idx += 256) {
            int j = idx & 7, lane = (idx >> 3) & 63, kc = (idx >> 9) & 3, mt = idx >> 11;
            int s = mt * 16 + (lane & 15);
            int k = kc * 32 + (lane >> 4) * 8 + j;
            int n = s & 63;
            float e = (float)(127 - k);
            float ex = __expf(e * drL[n]);
            float ph = e * diL[n];
            float v = (s < 64) ? ex * __cosf(ph) : ex * __sinf(ph);
            Vfrag[vbase + idx] = f2bf(v);
        }
    }
}

// ---------------- LayerNorm over H -> bf16 z ----------------
__global__ __launch_bounds__(256) void ln_kernel(
    const float* __restrict__ x, const float* __restrict__ tb,
    const float* __restrict__ ln_g, const float* __restrict__ ln_b,
    ushort_t* __restrict__ zbf)
{
    int gid = blockIdx.x * 256 + threadIdx.x;
    int b = gid >> 11, l = gid & 2047;
    const float* xp = x + (size_t)b * (Hh * Ll) + l;
    const float* tbp = tb + b * 256;
    float sum = 0.f, ssq = 0.f;
    #pragma unroll 8
    for (int h = 0; h < 256; ++h) {
        float v = xp[(size_t)h * Ll] + tbp[h];
        sum += v; ssq = fmaf(v, v, ssq);
    }
    float mean = sum * (1.f / 256.f);
    float var = fmaf(ssq, 1.f / 256.f, -mean * mean);
    float rstd = rsqrtf(var + 1e-5f);
    ushort_t* zp = zbf + (size_t)b * (Hh * Ll) + l;
    #pragma unroll 8
    for (int h = 0; h < 256; ++h) {
        float v = xp[(size_t)h * Ll] + tbp[h];
        zp[(size_t)h * Ll] = f2bf((v - mean) * rstd * ln_g[h] + ln_b[h]);
    }
}

// ---------------- mega SSM: z -> Q (MFMA) -> in-LDS scan -> conv (MFMA) -> gelu -> ya ----------------
// grid (h 256, cb 8); block handles (h, 4 b's), both directions; states never leave LDS.
__global__ __launch_bounds__(256) void ssm_mega_kernel(
    const ushort_t* __restrict__ zbf,
    const float* __restrict__ drg, const float* __restrict__ dig, const float* __restrict__ Dv,
    const ushort_t* __restrict__ Mfrag, const ushort_t* __restrict__ Vfrag,
    ushort_t* __restrict__ ya)
{
    __shared__ ushort_t Zs[64 * 136];
    __shared__ ushort_t Ssf[64 * 136];
    __shared__ ushort_t Ssb[64 * 136];
    __shared__ float Qb[2 * 128 * 17];
    int tid = threadIdx.x, lane = tid & 63, w = tid >> 6;
    int q = lane >> 4, cl = lane & 15;
    int h = blockIdx.x, cb = blockIdx.y;
    int b0 = cb * 4;
    // stage z rows (forward order)
    for (int i = tid; i < 1024; i += 256) {
        int bsub = i >> 8, t8 = (i & 255) * 8;
        const ushort_t* zrow = zbf + ((size_t)((b0 + bsub) * 256 + h) << 11);
        *(uint4v*)&Zs[(bsub * 16 + (t8 >> 7)) * 136 + (t8 & 127)] = *(const uint4v*)(zrow + t8);
    }
    float dr0 = drg[h * 64 + lane], di0 = dig[h * 64 + lane];
    float ex128 = __expf(128.f * dr0);
    float w128r = ex128 * __cosf(128.f * di0);
    float w128i = ex128 * __sinf(128.f * di0);
    float Dh = Dv[h];
    __syncthreads();
    const ushort_t* vbase = Vfrag + ((size_t)h << 14);
    const ushort_t* mbase0 = Mfrag + ((size_t)(h * 2) << 15);
    const ushort_t* mbase1 = Mfrag + ((size_t)(h * 2 + 1) << 15);
    // per-bsub: Q = V @ [z | z_rev] chunks (MFMA), then 16-step scan into Ssf/Ssb
    for (int bsub = 0; bsub < 4; ++bsub) {
        f32x4 qa[2][2] = {};   // [dir][i]
        #pragma unroll
        for (int kc = 0; kc < 4; ++kc) {
            int kk = kc * 32 + q * 8;
            bf16x8 bz = __builtin_bit_cast(bf16x8,
                *(const uint4v*)&Zs[(bsub * 16 + cl) * 136 + kk]);
            bf16x8 bzr = __builtin_bit_cast(bf16x8, rev8v(
                *(const uint4v*)&Zs[(bsub * 16 + (15 - cl)) * 136 + (120 - kk)]));
            #pragma unroll
            for (int i = 0; i < 2; ++i) {
                int mt = w * 2 + i;
                bf16x8 af = __builtin_bit_cast(bf16x8,
                    *(const uint4v*)(vbase + (((mt * 4 + kc) * 64 + lane) << 3)));
                qa[0][i] = __builtin_amdgcn_mfma_f32_16x16x32_bf16(af, bz, qa[0][i], 0, 0, 0);
                qa[1][i] = __builtin_amdgcn_mfma_f32_16x16x32_bf16(af, bzr, qa[1][i], 0, 0, 0);
            }
        }
        __syncthreads();   // previous scan's Qb reads complete
        #pragma unroll
        for (int d = 0; d < 2; ++d)
            #pragma unroll
            for (int i = 0; i < 2; ++i) {
                int mt = w * 2 + i;
                #pragma unroll
                for (int r = 0; r < 4; ++r)
                    Qb[d * 2176 + (mt * 16 + q * 4 + r) * 17 + cl] = qa[d][i][r];
            }
        __syncthreads();
        if (w < 2) {           // w=0: fwd scan, w=1: bwd scan (parallel waves)
            ushort_t* S = (w == 0) ? Ssf : Ssb;
            const float* Qp = Qb + w * 2176;
            float sre = 0.f, sim = 0.f;
            for (int cc = 0; cc < 16; ++cc) {
                S[(bsub * 16 + cc) * 136 + lane] = f2bf(sre);
                S[(bsub * 16 + cc) * 136 + 64 + lane] = f2bf(sim);
                float qre = Qp[lane * 17 + cc];
                float qim = Qp[(64 + lane) * 17 + cc];
                float nre = fmaf(w128r, sre, fmaf(-w128i, sim, qre));
                float nim = fmaf(w128r, sim, fmaf(w128i, sre, qim));
                sre = nre; sim = nim;
            }
        }
        __syncthreads();
    }
    // conv: y = M @ [z-chunk ; state], both dirs, 64 columns = 4 b x 16 chunks
    f32x4 accf[2][4] = {}, accb[2][4] = {};
    for (int kc = 0; kc < 8; ++kc) {
        int kk = (kc & 3) * 32 + q * 8;
        bf16x8 aff[2], afb[2];
        #pragma unroll
        for (int i = 0; i < 2; ++i) {
            int mt = w * 2 + i;
            aff[i] = __builtin_bit_cast(bf16x8, *(const uint4v*)(mbase0 + (((mt * 8 + kc) * 64 + lane) << 3)));
            afb[i] = __builtin_bit_cast(bf16x8, *(const uint4v*)(mbase1 + (((mt * 8 + kc) * 64 + lane) << 3)));
        }
        #pragma unroll
        for (int nt = 0; nt < 4; ++nt) {
            bf16x8 bff, bfb_;
            if (kc < 4) {
                bff  = __builtin_bit_cast(bf16x8, *(const uint4v*)&Zs[(nt * 16 + cl) * 136 + kk]);
                bfb_ = __builtin_bit_cast(bf16x8, rev8v(
                       *(const uint4v*)&Zs[(nt * 16 + (15 - cl)) * 136 + (120 - kk)]));
            } else {
                bff  = __builtin_bit_cast(bf16x8, *(const uint4v*)&Ssf[(nt * 16 + cl) * 136 + kk]);
                bfb_ = __builtin_bit_cast(bf16x8, *(const uint4v*)&Ssb[(nt * 16 + cl) * 136 + kk]);
            }
            #pragma unroll
            for (int i = 0; i < 2; ++i) {
                accf[i][nt] = __builtin_amdgcn_mfma_f32_16x16x32_bf16(aff[i], bff,  accf[i][nt], 0, 0, 0);
                accb[i][nt] = __builtin_amdgcn_mfma_f32_16x16x32_bf16(afb[i], bfb_, accb[i][nt], 0, 0, 0);
            }
        }
    }
    __syncthreads();           // conv reads of Ssf/Ssb done; reuse as Yf/Yb
    ushort_t* Yf = Ssf;
    ushort_t* Yb = Ssb;
    #pragma unroll
    for (int i = 0; i < 2; ++i) {
        int mt = w * 2 + i;
        #pragma unroll
        for (int nt = 0; nt < 4; ++nt) {
            int col = nt * 16 + cl;
            #pragma unroll
            for (int r = 0; r < 4; ++r) {
                int m = mt * 16 + q * 4 + r;
                Yf[col * 136 + m] = f2bf(accf[i][nt][r]);
                Yb[col * 136 + m] = f2bf(accb[i][nt][r]);
            }
        }
    }
    __syncthreads();
    // epilogue: ya = gelu(yf + yb_rev + D*z), coalesced vec8 writes
    for (int u = tid; u < 1024; u += 256) {
        int col = u >> 4, i0 = (u & 15) * 8;
        int bsub = col >> 4, c = col & 15;
        int colb = bsub * 16 + (15 - c);
        union { uint4v v; ushort_t s8[8]; } uf, uz, ub, uo;
        uf.v = *(const uint4v*)&Yf[col * 136 + i0];
        uz.v = *(const uint4v*)&Zs[col * 136 + i0];
        ub.v = rev8v(*(const uint4v*)&Yb[colb * 136 + (120 - i0)]);
        #pragma unroll
        for (int j = 0; j < 8; ++j) {
            float v = bf2f(uf.s8[j]) + bf2f(ub.s8[j]) + Dh * bf2f(uz.s8[j]);
            uo.s8[j] = f2bf(gelu_tanh(v));
        }
        ushort_t* yrow = ya + ((size_t)((b0 + bsub) * 256 + h) << 11);
        *(uint4v*)(yrow + c * 128 + i0) = uo.v;
    }
}

// ---------------- GEMM1: g = gate(Wc @ [ya; feat] + bc + x + tb) ----------------
__global__ __launch_bounds__(256, 4) void gemm1_kernel(
    const ushort_t* __restrict__ ya, const float* __restrict__ feat,
    const float* __restrict__ x, const float* __restrict__ tb,
    const float* __restrict__ bc, const ushort_t* __restrict__ wcf,
    ushort_t* __restrict__ g)
{
    __shared__ __align__(16) ushort_t XT[64 * 48];
    int tid = threadIdx.x;
    int w = tid >> 6, lane = tid & 63;
    int bx = blockIdx.x;
    int b = bx >> 5;
    int l0 = (bx & 31) << 6;
    f32x4 acc[4][4] = {};
    int kk = tid >> 3, ng = tid & 7;
    for (int kc = 0; kc < 9; ++kc) {
        int k = kc * 32 + kk;
        union { uint4v v; ushort_t s[8]; } u;
        if (k < 256) {
            u.v = *(const uint4v*)(ya + ((size_t)(b * 256 + k) << 11) + l0 + ng * 8);
        } else {
            const float* src = feat + (size_t)(b * 32 + (k - 256)) * Ll + l0 + ng * 8;
            #pragma unroll
            for (int j = 0; j < 8; ++j) u.s[j] = f2bf(src[j]);
        }
        #pragma unroll
        for (int j = 0; j < 8; ++j) XT[(ng * 8 + j) * 48 + kk] = u.s[j];
        __syncthreads();
        bf16x8 af[4], bfr[4];
        #pragma unroll
        for (int i = 0; i < 4; ++i) {
            const ushort_t* p = wcf + ((size_t)((w * 4 + i) * 9 + kc) * 64 + lane) * 8;
            af[i] = __builtin_bit_cast(bf16x8, *(const uint4v*)p);
        }
        #pragma unroll
        for (int nt = 0; nt < 4; ++nt) {
            const ushort_t* p = &XT[(nt * 16 + (lane & 15)) * 48 + (lane >> 4) * 8];
            bfr[nt] = __builtin_bit_cast(bf16x8, *(const uint4v*)p);
        }
        #pragma unroll
        for (int i = 0; i < 4; ++i)
            #pragma unroll
            for (int nt = 0; nt < 4; ++nt)
                acc[i][nt] = __builtin_amdgcn_mfma_f32_16x16x32_bf16(af[i], bfr[nt], acc[i][nt], 0, 0, 0);
        __syncthreads();
    }
    int q = lane >> 4, nl = lane & 15;
    #pragma unroll
    for (int i = 0; i < 4; ++i) {
        #pragma unroll
        for (int nt = 0; nt < 4; ++nt) {
            int n = l0 + nt * 16 + nl;
            #pragma unroll
            for (int r = 0; r < 4; ++r) {
                int m = (w * 4 + i) * 16 + q * 4 + r;
                size_t oi = (size_t)(b * 256 + m) * Ll + n;
                float v = acc[i][nt][r] + bc[m] + tb[b * 256 + m] + x[oi];
                g[oi] = f2bf(gate_fn(v));
            }
        }
    }
}

// ---------------- GEMM2: o1 = W1@g + b1 + x ; o2 = W2@g + b2 ----------------
__global__ __launch_bounds__(256, 4) void gemm2_kernel(
    const ushort_t* __restrict__ g, const float* __restrict__ x,
    const float* __restrict__ b12, const ushort_t* __restrict__ w12f,
    float* __restrict__ out)
{
    __shared__ __align__(16) ushort_t XT[64 * 48];
    int tid = threadIdx.x;
    int w = tid >> 6, lane = tid & 63;
    int bx = blockIdx.x;
    int half = blockIdx.y;
    int b = bx >> 5;
    int l0 = (bx & 31) << 6;
    f32x4 acc[4][4] = {};
    int kk = tid >> 3, ng = tid & 7;
    for (int kc = 0; kc < 8; ++kc) {
        int k = kc * 32 + kk;
        union { uint4v v; ushort_t s[8]; } u;
        u.v = *(const uint4v*)(g + (size_t)(b * 256 + k) * Ll + l0 + ng * 8);
        #pragma unroll
        for (int j = 0; j < 8; ++j) XT[(ng * 8 + j) * 48 + kk] = u.s[j];
        __syncthreads();
        bf16x8 af[4], bfr[4];
        #pragma unroll
        for (int i = 0; i < 4; ++i) {
            int mtg = half * 16 + w * 4 + i;
            const ushort_t* p = w12f + ((size_t)(mtg * 8 + kc) * 64 + lane) * 8;
            af[i] = __builtin_bit_cast(bf16x8, *(const uint4v*)p);
        }
        #pragma unroll
        for (int nt = 0; nt < 4; ++nt) {
            const ushort_t* p = &XT[(nt * 16 + (lane & 15)) * 48 + (lane >> 4) * 8];
            bfr[nt] = __builtin_bit_cast(bf16x8, *(const uint4v*)p);
        }
        #pragma unroll
        for (int i = 0; i < 4; ++i)
            #pragma unroll
            for (int nt = 0; nt < 4; ++nt)
                acc[i][nt] = __builtin_amdgcn_mfma_f32_16x16x32_bf16(af[i], bfr[nt], acc[i][nt], 0, 0, 0);
        __syncthreads();
    }
    int q = lane >> 4, nl = lane & 15;
    #pragma unroll
    for (int i = 0; i < 4; ++i) {
        #pragma unroll
        for (int nt = 0; nt < 4; ++nt) {
            int n = l0 + nt * 16 + nl;
            #pragma unroll
            for (int r = 0; r < 4; ++r) {
                int m = (w * 4 + i) * 16 + q * 4 + r;
                size_t oi = (size_t)(b * 256 + m) * Ll + n;
                float v = acc[i][nt][r] + b12[half * 256 + m];
                if (half == 0) out[oi] = v + x[oi];
                else out[(size_t)BHL + oi] = v;
            }
        }
    }
}

extern "C" void kernel_launch(void* const* d_in, const int* in_sizes, int n_in,
                              void* d_out, int out_size, void* d_ws, size_t ws_size,
                              hipStream_t stream) {
    const float* x      = (const float*)d_in[0];
    const float* t      = (const float*)d_in[1];
    const float* feat   = (const float*)d_in[2];
    const float* Wt     = (const float*)d_in[3];
    const float* bt     = (const float*)d_in[4];
    const float* ln_g   = (const float*)d_in[5];
    const float* ln_b   = (const float*)d_in[6];
    const float* log_dt = (const float*)d_in[7];
    const float* logA   = (const float*)d_in[8];
    const float* Aimg   = (const float*)d_in[9];
    const float* C_re   = (const float*)d_in[10];
    const float* C_im   = (const float*)d_in[11];
    const float* Dv     = (const float*)d_in[12];
    const float* Wout   = (const float*)d_in[13];
    const float* bout   = (const float*)d_in[14];
    const float* W1     = (const float*)d_in[15];
    const float* b1     = (const float*)d_in[16];
    const float* W2     = (const float*)d_in[17];
    const float* b2     = (const float*)d_in[18];
    const float* Wf     = (const float*)d_in[19];
    const float* bfb    = (const float*)d_in[20];

    // d_out (128 MiB): zbf [0,32Mi) | ya [32,64Mi) ; later fully overwritten by out
    char* ob = (char*)d_out;
    ushort_t* zbf = (ushort_t*)ob;
    ushort_t* yab = (ushort_t*)(ob + 33554432);
    float*    out = (float*)d_out;

    // ws: Mfrag 32 MiB (aliased by g after mega) | Vfrag 8 MiB | small tables
    char* ws = (char*)d_ws;
    ushort_t* Mfrag = (ushort_t*)ws;
    ushort_t* gbuf  = (ushort_t*)ws;                  // alias: g overwrites Mfrag (dead by gemm1)
    ushort_t* Vfrag = (ushort_t*)(ws + 33554432);
    char* ws2 = ws + 33554432 + 8388608;
    float* tb   = (float*)ws2;
    float* drg  = (float*)(ws2 + 32768);
    float* dig  = (float*)(ws2 + 98304);
    float* bc   = (float*)(ws2 + 163840);
    float* b12  = (float*)(ws2 + 164864);
    ushort_t* wcf  = (ushort_t*)(ws2 + 166912);
    ushort_t* w12f = (ushort_t*)(ws2 + 314368);

    prep_kernel<<<96, 256, 0, stream>>>(t, Wt, bt, Wout, Wf, bout, bfb, W1, b1, W2, b2,
                                        tb, bc, b12, wcf, w12f);
    prep2_kernel<<<512, 256, 0, stream>>>(log_dt, logA, Aimg, C_re, C_im, drg, dig, Mfrag, Vfrag);
    ln_kernel<<<256, 256, 0, stream>>>(x, tb, ln_g, ln_b, zbf);
    ssm_mega_kernel<<<dim3(256, 8), 256, 0, stream>>>(zbf, drg, dig, Dv, Mfrag, Vfrag, yab);
    gemm1_kernel<<<1024, 256, 0, stream>>>(yab, feat, x, tb, bc, wcf, gbuf);
    gemm2_kernel<<<dim3(1024, 2), 256, 0, stream>>>(gbuf, x, b12, w12f, out);
}